// Round 11
// baseline (236.779 us; speedup 1.0000x reference)
//
#include <hip/hip_runtime.h>

// AttentionXL (TransformerXL relative attention), MI355X gfx950.
// Round 22: true 4-dispatch pipeline + split-K proj.
//  - Round 10's memset node canceled the removed combine dispatch (5 nodes
//    either way). Flag-zeroing now folded into prep_k (idle block 5631)
//    -> genuinely 4 graph nodes: prep -> gemm3 -> flash(+merge) -> proj.
//  - proj GEMM was 128 blocks (half the CUs idle, block-latency-bound).
//    Now split-K x2 (256 blocks, K=512 each) with the proven fence-free
//    last-arriver merge; partials in the po region (dead after flash),
//    proj flags at flags+512 (prep zeroes 1024 entries).
// flash_k unchanged from round 10 (stable ~60.5us reference).

typedef unsigned short u16;
typedef short short8 __attribute__((ext_vector_type(8)));
typedef float f32x4 __attribute__((ext_vector_type(4)));
typedef unsigned uint4v __attribute__((ext_vector_type(4)));

#define BSZ 4
#define PREV 512

__device__ __forceinline__ float b2f(u16 u) {
  union { unsigned int i; float f; } x; x.i = ((unsigned int)u) << 16; return x.f;
}
__device__ __forceinline__ u16 f2b(float f) {
  union { float f; unsigned int i; } x; x.f = f;
  unsigned int u = x.i;
  return (u16)((u + 0x7fffu + ((u >> 16) & 1u)) >> 16);
}
__device__ __forceinline__ void storeC(u16* C, size_t idx, float v) { C[idx] = f2b(v); }
__device__ __forceinline__ void storeC(float* C, size_t idx, float v) { C[idx] = v; }

// device-coherent (sc-bit) store/load: write-through to / read from the
// coherent point; RELAXED => no cache-maintenance instructions.
__device__ __forceinline__ void coh_store(float* p, float v) {
  __hip_atomic_store(p, v, __ATOMIC_RELAXED, __HIP_MEMORY_SCOPE_AGENT);
}
__device__ __forceinline__ float coh_load(const float* p) {
  return __hip_atomic_load(p, __ATOMIC_RELAXED, __HIP_MEMORY_SCOPE_AGENT);
}

// async 16B/lane global->LDS DMA; lds dest = wave-uniform base + lane*16
__device__ __forceinline__ void load_lds16(const u16* g, void* l) {
  __builtin_amdgcn_global_load_lds(
      (const __attribute__((address_space(1))) unsigned int*)g,
      (__attribute__((address_space(3))) unsigned int*)l, 16, 0, 0);
}

// Packed operand layout: matrix [R][K] tiled into 16x32 chunks of 512 u16.
// chunk = (row/16)*(K/32) + k/32; within-chunk = frag order
// [quad=(k>>3)&3][ml=row&15][e=k&7].
__device__ __forceinline__ size_t pidx8(int row, int k, int K32) {
  return (((size_t)((row >> 4) * K32 + (k >> 5))) << 9) +
         (((k >> 3) & 3) << 7) + ((row & 15) << 3);
}

// ---------------------------------------------------------------------------
// prep: convert (blocks 0..3583) + weight transpose (3584..5631), packed out.
// Idle block 5631 (its transpose tile is out of range) zeroes the 1024 merge
// flags used by flash_k and the split-K proj -- no memset dispatch needed.
// ---------------------------------------------------------------------------
__global__ __launch_bounds__(256)
void prep_k(const float* __restrict__ s0, const float* __restrict__ s1,
            const float* __restrict__ s2, u16* __restrict__ d0,
            u16* __restrict__ d1, u16* __restrict__ d2,
            const float* __restrict__ W0, const float* __restrict__ W1,
            const float* __restrict__ W2, const float* __restrict__ W3,
            u16* __restrict__ T0, u16* __restrict__ T1,
            u16* __restrict__ T2, u16* __restrict__ T3,
            unsigned* __restrict__ flags) {
  __shared__ u16 ld[64 * 66];
  const int bxg = blockIdx.x, tid = threadIdx.x;
  if (bxg == 5631) {              // idle transpose block: zero merge flags
    uint4v z = {0u, 0u, 0u, 0u};
    reinterpret_cast<uint4v*>(flags)[tid] = z;   // 256 x 16B = 1024 uints
    return;
  }
  if (bxg < 3584) {
    const float* s; u16* d; size_t base;
    if (bxg < 2048)      { s = s0; d = d0; base = (size_t)bxg * 2048; }
    else if (bxg < 3072) { s = s1; d = d1; base = (size_t)(bxg - 2048) * 2048; }
    else                 { s = s2; d = d2; base = (size_t)(bxg - 3072) * 2048; }
    size_t i = base + (size_t)tid * 8;
    const f32x4* p = reinterpret_cast<const f32x4*>(s + i);
    f32x4 a = p[0], b = p[1];
    short8 r;
#pragma unroll
    for (int e = 0; e < 4; e++) { r[e] = (short)f2b(a[e]); r[e + 4] = (short)f2b(b[e]); }
    int row = (int)(i >> 10), k = (int)(i & 1023);
    *reinterpret_cast<short8*>(d + pidx8(row, k, 32)) = r;
    return;
  }
  const int l = bxg - 3584;
  const int z = l >> 9;
  const int rem = l & 511;
  const int bx = rem & 31, by = rem >> 5;
  const float* W; u16* T; int N;
  if (z == 0)      { W = W0; T = T0; N = 2048; }
  else if (z == 1) { W = W1; T = T1; N = 1024; }
  else if (z == 2) { W = W2; T = T2; N = 1024; }
  else             { W = W3; T = T3; N = 1024; }
  const int n0 = bx * 64, k0 = by * 64;
  if (n0 >= N) return;

#pragma unroll
  for (int rep = 0; rep < 16; rep++) {
    int idx = tid + 256 * rep;
    int kk = idx >> 6, nn = idx & 63;
    ld[kk * 66 + nn] = f2b(W[(size_t)(k0 + kk) * N + n0 + nn]);
  }
  __syncthreads();
#pragma unroll
  for (int rep = 0; rep < 2; rep++) {
    int idx = tid + 256 * rep;           // 0..511
    int nn = idx >> 3, k8 = (idx & 7) * 8;
    short8 r;
#pragma unroll
    for (int e = 0; e < 8; e++) r[e] = (short)ld[(k8 + e) * 66 + nn];
    *reinterpret_cast<short8*>(T + pidx8(n0 + nn, k0 + k8, 32)) = r;
  }
}

// ---------------------------------------------------------------------------
// GEMM core: C = A @ BT^T + bias, A/BT packed. 128x128 tile, BK=64,
// K-range [kbeg, kend).
// MODE 0: row-major C. MODE 1 (kv): Kt2/Vt2 frag-tile order. MODE 2: Rt.
// MODE 3: split-K partial with fence-free last-arriver merge (scratch =
//   fp32 partials, gflags = per-tile flag, part = K-half index).
// ---------------------------------------------------------------------------
template <typename OT, int MODE>
__device__ __forceinline__ void gemm_core(
    short* __restrict__ at, short* __restrict__ bt,
    const u16* __restrict__ A, const u16* __restrict__ BT,
    const float* __restrict__ bias, OT* __restrict__ C, u16* __restrict__ C2,
    int N, int K, int bx, int by, int kbeg, int kend,
    float* scratch, unsigned* gflags, int part)
{
  const int tid = threadIdx.x;
  const int lane = tid & 63, w = tid >> 6;
  const int wr = w >> 1, wc = w & 1;
  const int quad = lane >> 4, ml = lane & 15;
  const int row0 = by * 128, col0 = bx * 128;
  const int K32 = K >> 5;

  f32x4 acc[4][4];
  const f32x4 fzero = {0.f, 0.f, 0.f, 0.f};
#pragma unroll
  for (int i = 0; i < 4; i++)
#pragma unroll
    for (int j = 0; j < 4; j++) acc[i][j] = fzero;

  for (int k0 = kbeg; k0 < kend; k0 += 64) {
    __syncthreads();  // previous tile fully consumed
#pragma unroll
    for (int i = 0; i < 4; i++) {
      int c = 4 * w + i;                 // chunk index 0..15
      int mc = c >> 1, kc = c & 1;
      size_t ca = ((size_t)(((row0 >> 4) + mc) * K32 + (k0 >> 5) + kc)) << 9;
      size_t cb = ((size_t)(((col0 >> 4) + mc) * K32 + (k0 >> 5) + kc)) << 9;
      load_lds16(A + ca + lane * 8, (void*)(at + c * 512));
      load_lds16(BT + cb + lane * 8, (void*)(bt + c * 512));
    }
    __syncthreads();  // drains vmcnt; staging visible

    short8 af[4][2], bf[4][2];
#pragma unroll
    for (int mc = 0; mc < 4; mc++)
#pragma unroll
      for (int kc = 0; kc < 2; kc++)
        af[mc][kc] = *reinterpret_cast<const short8*>(at + ((((wr * 4 + mc) * 2 + kc) * 64) + lane) * 8);
#pragma unroll
    for (int nc = 0; nc < 4; nc++)
#pragma unroll
      for (int kc = 0; kc < 2; kc++)
        bf[nc][kc] = *reinterpret_cast<const short8*>(bt + ((((wc * 4 + nc) * 2 + kc) * 64) + lane) * 8);

#pragma unroll
    for (int mc = 0; mc < 4; mc++)
#pragma unroll
      for (int nc = 0; nc < 4; nc++)
#pragma unroll
        for (int kc = 0; kc < 2; kc++)
          acc[mc][nc] = __builtin_amdgcn_mfma_f32_16x16x32_bf16(af[mc][kc], bf[nc][kc], acc[mc][nc], 0, 0, 0);
  }

  if constexpr (MODE != 3) {
#pragma unroll
    for (int nc = 0; nc < 4; nc++) {
      int col = col0 + wc * 64 + nc * 16 + ml;
      float bv = bias[col];
#pragma unroll
      for (int mc = 0; mc < 4; mc++) {
#pragma unroll
        for (int reg = 0; reg < 4; reg++) {
          int row = row0 + wr * 64 + mc * 16 + quad * 4 + reg;
          float val = acc[mc][nc][reg] + bv;
          if constexpr (MODE == 0) {
            storeC(C, (size_t)row * N + col, val);
          } else if constexpr (MODE == 1) {
            int j = row >> 2, bb = row & 3;
            int tile = j >> 6, jl = j & 63;
            if (col < 1024) {  // K half: frag (n=j, k=d)
              int h = col >> 6, d = col & 63;
              int ncj = jl >> 4, nlj = jl & 15, kcd = d >> 5, qdd = (d >> 3) & 3, jjd = d & 7;
              C[((size_t)(bb * 16 + h) * 16 + tile) * 4096 +
                ((ncj * 2 + kcd) * 64 + qdd * 16 + nlj) * 8 + jjd] = f2b(val);
            } else {           // V half: frag (n=d, k=j)
              int c2 = col - 1024;
              int h = c2 >> 6, d = c2 & 63;
              int ncd = d >> 4, nld = d & 15, kcj = jl >> 5, qdj = (jl >> 3) & 3, jjj = jl & 7;
              C2[((size_t)(bb * 16 + h) * 16 + tile) * 4096 +
                 ((kcj * 4 + ncd) * 64 + qdj * 16 + nld) * 8 + jjj] = f2b(val);
            }
          } else {             // MODE 2: Rt[h][rel][d]
            int h = col >> 6, d = col & 63;
            C[((size_t)h * 1024 + row) * 64 + d] = f2b(val);
          }
        }
      }
    }
  } else {
    // ---- MODE 3: split-K last-arriver merge (fence-free, proven pattern)
    __shared__ unsigned psec;
    const int tp = by * 8 + bx;
    float* sc = scratch + ((size_t)part * 128 + tp) * 16384;
#pragma unroll
    for (int nc = 0; nc < 4; nc++)
#pragma unroll
      for (int mc = 0; mc < 4; mc++)
#pragma unroll
        for (int reg = 0; reg < 4; reg++) {
          int rl = wr * 64 + mc * 16 + quad * 4 + reg;
          int cl = wc * 64 + nc * 16 + ml;
          coh_store(sc + rl * 128 + cl, acc[mc][nc][reg]);
        }
    __syncthreads();   // drains vmcnt: partial complete at coherent point
    if (tid == 0)
      psec = __hip_atomic_fetch_add(gflags + tp, 1u, __ATOMIC_RELAXED,
                                    __HIP_MEMORY_SCOPE_AGENT);
    __syncthreads();
    if (psec) {
      const float* sp = scratch + ((size_t)(part ^ 1) * 128 + tp) * 16384;
#pragma unroll
      for (int nc = 0; nc < 4; nc++) {
        int col = col0 + wc * 64 + nc * 16 + ml;
        float bv = bias[col];
#pragma unroll
        for (int mc = 0; mc < 4; mc++)
#pragma unroll
          for (int reg = 0; reg < 4; reg++) {
            int rl = wr * 64 + mc * 16 + quad * 4 + reg;
            int cl = wc * 64 + nc * 16 + ml;
            int row = row0 + rl;
            float val = acc[mc][nc][reg] + coh_load(sp + rl * 128 + cl) + bv;
            C[(size_t)row * N + col] = val;
          }
      }
    }
  }
}

// ---------------------------------------------------------------------------
// gemm3: kv (512 blocks) + q (128) + r (64) in one 704-block dispatch.
// ---------------------------------------------------------------------------
__global__ __launch_bounds__(256, 2)
void gemm3_k(const u16* __restrict__ fibf, const u16* __restrict__ WkvT,
             const float* __restrict__ b_kv, u16* __restrict__ Kt2, u16* __restrict__ Vt2,
             const u16* __restrict__ inbf, const u16* __restrict__ WqT,
             const float* __restrict__ b_q, u16* __restrict__ qq,
             const u16* __restrict__ pebf, const u16* __restrict__ WposT,
             const float* __restrict__ b_pos, u16* __restrict__ Rt)
{
  __shared__ __align__(16) short at[8192];
  __shared__ __align__(16) short bt[8192];
  const int id = blockIdx.x;
  if (id < 512) {
    gemm_core<u16, 1>(at, bt, fibf, WkvT, b_kv, Kt2, Vt2, 2048, 1024,
                      id & 15, id >> 4, 0, 1024, nullptr, nullptr, 0);
  } else if (id < 640) {
    const int l = id - 512;
    gemm_core<u16, 0>(at, bt, inbf, WqT, b_q, qq, (u16*)nullptr, 1024, 1024,
                      l & 7, l >> 3, 0, 1024, nullptr, nullptr, 0);
  } else {
    const int l = id - 640;
    gemm_core<u16, 2>(at, bt, pebf, WposT, b_pos, Rt, (u16*)nullptr, 1024, 1024,
                      l & 7, l >> 3, 0, 1024, nullptr, nullptr, 0);
  }
}

// ---------------------------------------------------------------------------
// proj: split-K x2 (256 blocks, K=512 each), last-arriver merge into out.
// ---------------------------------------------------------------------------
__global__ __launch_bounds__(256, 2)
void gemm_proj_k(const u16* __restrict__ A, const u16* __restrict__ BT,
                 const float* __restrict__ bias, float* __restrict__ C,
                 float* __restrict__ scratch, unsigned* __restrict__ gflags)
{
  __shared__ __align__(16) short at[8192];
  __shared__ __align__(16) short bt[8192];
  const int id = blockIdx.x;          // 0..255
  const int part = id >> 7, l = id & 127;
  gemm_core<float, 3>(at, bt, A, BT, bias, C, (u16*)nullptr, 1024, 1024,
                      l & 7, l >> 3, part * 512, part * 512 + 512,
                      scratch, gflags, part);
}

// ---------------------------------------------------------------------------
// Split-j fused flash-XL (round-6 body) + fence-free last-arriver merge.
// 16 blocks/bh (it 0..7 x seg 0..1), longest-first; 4 blocks/CU resident.
// ---------------------------------------------------------------------------
__global__ __launch_bounds__(256, 4)
void flash_k(const u16* __restrict__ q, const u16* __restrict__ Kt2,
             const u16* __restrict__ Vt2, const u16* __restrict__ Rt,
             const float* __restrict__ u, const float* __restrict__ v,
             float* __restrict__ po, float* __restrict__ pm,
             float* __restrict__ pl, u16* __restrict__ av,
             unsigned* __restrict__ flags)
{
  __shared__ __align__(16) short kb[4096];
  __shared__ __align__(16) short vb[4096];
  __shared__ __align__(16) short pt[4][1024];
  __shared__ unsigned sec;

  const int tid = threadIdx.x, lane = tid & 63, w = tid >> 6;
  short* ptw = pt[w];
  const int quad = lane >> 4, ml = lane & 15;
  const int x = blockIdx.x;
  const int it = 7 - (x >> 1), s = x & 1;     // longest i-tiles first
  const int nt = it + 9;
  const int nt0 = (nt + 1) >> 1;
  const int ts = s ? nt0 : 0, te = s ? nt : nt0;

  const int b = blockIdx.y, h = blockIdx.z;
  const int bh = b * 16 + h;
  const int i0 = it * 64, ig0 = i0 + w * 16;

  const u16* Kbase = Kt2 + ((size_t)(b * 16 + h) * 16) * 4096;
  const u16* Vbase = Vt2 + ((size_t)(b * 16 + h) * 16) * 4096;
  const u16* Rp = Rt + (size_t)h * 65536;

  // Q fragments, pre-scaled by 1/8: rows ig0+ml, k = kc*32+quad*8+e
  short8 qu[2], qvf[2];
  {
    int ig = ig0 + ml;
#pragma unroll
    for (int kc = 0; kc < 2; kc++) {
      int dbase = kc * 32 + quad * 8;
      short8 qq = *reinterpret_cast<const short8*>(q + ((size_t)ig * BSZ + b) * 1024 + h * 64 + dbase);
      const f32x4* up = reinterpret_cast<const f32x4*>(u + h * 64 + dbase);
      const f32x4* vp = reinterpret_cast<const f32x4*>(v + h * 64 + dbase);
      f32x4 u0 = up[0], u1 = up[1], v0 = vp[0], v1 = vp[1];
#pragma unroll
      for (int e = 0; e < 8; e++) {
        float qf = b2f((u16)qq[e]);
        float uu = (e < 4) ? u0[e] : u1[e - 4];
        float vv = (e < 4) ? v0[e] : v1[e - 4];
        qu[kc][e]  = (short)f2b((qf + uu) * 0.125f);
        qvf[kc][e] = (short)f2b((qf + vv) * 0.125f);
      }
    }
  }

  short8 kones;
#pragma unroll
  for (int e = 0; e < 8; e++) kones[e] = (short)0x3F80;

  const f32x4 fzero = {0.f, 0.f, 0.f, 0.f};
  f32x4 o_acc[4];
#pragma unroll
  for (int i = 0; i < 4; i++) o_acc[i] = fzero;
  float m_run[4], l_run[4];
#pragma unroll
  for (int i = 0; i < 4; i++) { m_run[i] = -1e30f; l_run[i] = 0.f; }

  // ---- prologue: prefetch tile ts's identity chunks into registers
  short8 pk0, pk1, pv0, pv1;
  {
    const u16* kg = Kbase + (size_t)ts * 4096;
    const u16* vg = Vbase + (size_t)ts * 4096;
    pk0 = *reinterpret_cast<const short8*>(kg + tid * 8);
    pk1 = *reinterpret_cast<const short8*>(kg + 2048 + tid * 8);
    pv0 = *reinterpret_cast<const short8*>(vg + tid * 8);
    pv1 = *reinterpret_cast<const short8*>(vg + 2048 + tid * 8);
  }

  for (int t = ts; t < te; t++) {
    const int j0 = t * 64;
    __syncthreads();  // previous tile fully consumed
    *reinterpret_cast<short8*>(kb + tid * 8) = pk0;
    *reinterpret_cast<short8*>(kb + 2048 + tid * 8) = pk1;
    *reinterpret_cast<short8*>(vb + tid * 8) = pv0;
    *reinterpret_cast<short8*>(vb + 2048 + tid * 8) = pv1;
    __syncthreads();  // staging visible

    if (t + 1 < te) {
      const u16* kg = Kbase + (size_t)(t + 1) * 4096;
      const u16* vg = Vbase + (size_t)(t + 1) * 4096;
      pk0 = *reinterpret_cast<const short8*>(kg + tid * 8);
      pk1 = *reinterpret_cast<const short8*>(kg + 2048 + tid * 8);
      pv0 = *reinterpret_cast<const short8*>(vg + tid * 8);
      pv1 = *reinterpret_cast<const short8*>(vg + 2048 + tid * 8);
    }

    // ---- content scores: K B-frags from LDS
    f32x4 sc[4];
#pragma unroll
    for (int nc = 0; nc < 4; nc++) {
      sc[nc] = fzero;
#pragma unroll
      for (int kc = 0; kc < 2; kc++) {
        short8 kf = *reinterpret_cast<const short8*>(kb + ((nc * 2 + kc) * 64 + lane) * 8);
        sc[nc] = __builtin_amdgcn_mfma_f32_16x16x32_bf16(qu[kc], kf, sc[nc], 0, 0, 0);
      }
    }
    // ---- position strip: R B-frags direct from global
    const int relstart = j0 - ig0 + 496;  // >= 0
    f32x4 p2[5];
#pragma unroll
    for (int c = 0; c < 5; c++) {
      p2[c] = fzero;
      int rel = relstart + c * 16 + ml;
      if (rel > 1023) rel = 1023;  // clamped rows are masked below
      const u16* rp = Rp + (size_t)rel * 64 + quad * 8;
#pragma unroll
      for (int kc = 0; kc < 2; kc++) {
        short8 rf = *reinterpret_cast<const short8*>(rp + kc * 32);
        p2[c] = __builtin_amdgcn_mfma_f32_16x16x32_bf16(qvf[kc], rf, p2[c], 0, 0, 0);
      }
    }

    // ---- rel-shift gather + mask + online softmax
    const bool anymask = (j0 + 63) > (ig0 + PREV);
    float pv_[4][4];
    float tmax[4] = {-1e30f, -1e30f, -1e30f, -1e30f};
#pragma unroll
    for (int reg = 0; reg < 4; reg++) {
      int rowl = quad * 4 + reg;
      int src = quad * 16 + ((ml - rowl - 1) & 15);
      bool hi = ml > rowl;
      float sh[5];
#pragma unroll
      for (int c = 0; c < 5; c++) sh[c] = __shfl(p2[c][reg], src, 64);
#pragma unroll
      for (int nc = 0; nc < 4; nc++) {
        float sv = sc[nc][reg] + (hi ? sh[nc + 1] : sh[nc]);
        if (anymask) {
          int jg = j0 + nc * 16 + ml;
          if (jg > ig0 + rowl + PREV) sv = -1e30f;
        }
        pv_[nc][reg] = sv;
        tmax[reg] = fmaxf(tmax[reg], sv);
      }
    }
#pragma unroll
    for (int reg = 0; reg < 4; reg++) {
      float tm = tmax[reg];
#pragma unroll
      for (int off = 1; off < 16; off <<= 1) tm = fmaxf(tm, __shfl_xor(tm, off, 64));
      float mnew = fmaxf(m_run[reg], tm);
      float alpha = __expf(m_run[reg] - mnew);
#pragma unroll
      for (int nc = 0; nc < 4; nc++)
        pv_[nc][reg] = __expf(pv_[nc][reg] - mnew);
      l_run[reg] *= alpha;
      m_run[reg] = mnew;
#pragma unroll
      for (int nc = 0; nc < 4; nc++) o_acc[nc][reg] *= alpha;
    }

    // ---- P (C layout) -> bf16 A-frag via per-wave LDS
#pragma unroll
    for (int nc = 0; nc < 4; nc++) {
      int jl = nc * 16 + ml;
      int kc = nc >> 1, qdj = (jl >> 3) & 3, jj = ml & 7;
#pragma unroll
      for (int reg = 0; reg < 4; reg++) {
        int rowl = quad * 4 + reg;
        ptw[(kc * 64 + qdj * 16 + rowl) * 8 + jj] = (short)f2b(pv_[nc][reg]);
      }
    }
    short8 pf[2];
    pf[0] = *reinterpret_cast<const short8*>(ptw + (0 * 64 + lane) * 8);
    pf[1] = *reinterpret_cast<const short8*>(ptw + (1 * 64 + lane) * 8);

    // ---- row-sum of P via ones-MFMA (concurrent with PV on the MFMA pipe)
    f32x4 lsum = fzero;
    lsum = __builtin_amdgcn_mfma_f32_16x16x32_bf16(pf[0], kones, lsum, 0, 0, 0);
    lsum = __builtin_amdgcn_mfma_f32_16x16x32_bf16(pf[1], kones, lsum, 0, 0, 0);

    // ---- PV: V B-frags from LDS
#pragma unroll
    for (int ncd = 0; ncd < 4; ncd++)
#pragma unroll
      for (int kc = 0; kc < 2; kc++) {
        short8 vf = *reinterpret_cast<const short8*>(vb + ((kc * 4 + ncd) * 64 + lane) * 8);
        o_acc[ncd] = __builtin_amdgcn_mfma_f32_16x16x32_bf16(pf[kc], vf, o_acc[ncd], 0, 0, 0);
      }
#pragma unroll
    for (int reg = 0; reg < 4; reg++) l_run[reg] += lsum[reg];
  }

  // ---- epilogue 1: coherent (sc-bit) stores of own partials (slot s)
#pragma unroll
  for (int reg = 0; reg < 4; reg++) {
    int ig = ig0 + quad * 4 + reg;
    size_t ridx = (size_t)(s * 512 + ig) * 64 + bh;
    if (ml == 0) { coh_store(pm + ridx, m_run[reg]); coh_store(pl + ridx, l_run[reg]); }
#pragma unroll
    for (int ncd = 0; ncd < 4; ncd++)
      coh_store(po + ridx * 64 + ncd * 16 + ml, o_acc[ncd][reg]);
  }

  // ---- epilogue 2: last arriver merges both segments, writes packed av.
  __syncthreads();   // drains vmcnt: coherent stores complete before flag RMW
  if (tid == 0) {
    unsigned old = __hip_atomic_fetch_add(flags + ((x >> 1) * 64 + bh), 1u,
                                          __ATOMIC_RELAXED, __HIP_MEMORY_SCOPE_AGENT);
    sec = old;                     // 1 => we arrived second
  }
  __syncthreads();
  if (sec) {
#pragma unroll
    for (int reg = 0; reg < 4; reg++) {
      int ig = ig0 + quad * 4 + reg;
      size_t prid = (size_t)((s ^ 1) * 512 + ig) * 64 + bh;
      float m2 = coh_load(pm + prid), l2 = coh_load(pl + prid);
      float m1 = m_run[reg], l1 = l_run[reg];
      float m = fmaxf(m1, m2);
      float a1 = __expf(m1 - m), a2 = __expf(m2 - m);
      float linv = 1.f / (l1 * a1 + l2 * a2);
      int row = ig * 4 + b;
#pragma unroll
      for (int ncd = 0; ncd < 4; ncd++) {
        int d = ncd * 16 + ml;
        float o2 = coh_load(po + prid * 64 + d);
        float val = (o_acc[ncd][reg] * a1 + o2 * a2) * linv;
        int k = h * 64 + d;
        av[pidx8(row, k, 32) + (k & 7)] = f2b(val);
      }
    }
  }
}

// ---------------------------------------------------------------------------
extern "C" void kernel_launch(void* const* d_in, const int* in_sizes, int n_in,
                              void* d_out, int out_size, void* d_ws, size_t ws_size,
                              hipStream_t stream) {
  (void)in_sizes; (void)n_in; (void)out_size; (void)ws_size;

  const float* inputs  = (const float*)d_in[0];   // (512,4,1024)
  const float* pos_emb = (const float*)d_in[1];   // (1024,1,1024)
  const float* full_in = (const float*)d_in[2];   // (1024,4,1024)
  const float* u       = (const float*)d_in[3];   // (16,64)
  const float* v       = (const float*)d_in[4];   // (16,64)
  const float* W_kv    = (const float*)d_in[5];   // (1024,2048)
  const float* b_kv    = (const float*)d_in[6];   // (2048,)
  const float* W_q     = (const float*)d_in[7];   // (1024,1024)
  const float* b_q     = (const float*)d_in[8];
  const float* W_pos   = (const float*)d_in[9];   // (1024,1024)
  const float* b_pos   = (const float*)d_in[10];
  const float* W_proj  = (const float*)d_in[11];  // (1024,1024)
  const float* b_proj  = (const float*)d_in[12];
  float* out = (float*)d_out;
  char* ws = (char*)d_ws;

  u16* Kt2   = (u16*)(ws);                  //  8 MB: frag-tile order
  u16* Vt2   = (u16*)(ws + ( 8u << 20));    //  8 MB
  u16* qq    = (u16*)(ws + (16u << 20));    //  4 MB row-major
  u16* Rt    = (u16*)(ws + (20u << 20));    //  2 MB [16 h][1024 rel][64 d]
  u16* av    = (u16*)(ws + (22u << 20));    //  4 MB packed
  u16* WkvT  = (u16*)(ws + (26u << 20));    //  4 MB packed
  u16* WqT   = (u16*)(ws + (30u << 20));    //  2 MB packed
  u16* WposT = (u16*)(ws + (32u << 20));    //  2 MB packed
  u16* WprojT= (u16*)(ws + (34u << 20));    //  2 MB packed
  u16* fibf  = (u16*)(ws + (36u << 20));    //  8 MB packed (dead after gemm3)
  u16* inbf  = (u16*)(ws + (44u << 20));    //  4 MB packed (dead after gemm3)
  u16* pebf  = (u16*)(ws + (48u << 20));    //  2 MB packed (dead after gemm3)
  float* po  = (float*)(ws + (36u << 20));  // 16 MB flash partials; reused as
                                            //        proj split-K scratch
  float* pm  = (float*)(ws + (52u << 20));  // 256 KB partial m
  float* pl  = (float*)(ws + (52u << 20) + (256u << 10));  // 256 KB partial l
  unsigned* flags = (unsigned*)(ws + (56u << 20));  // 4 KB merge flags
                                                    // [0,512) flash, [512,640) proj

  // --- precompute (converts + weight transposes + flag zeroing, one dispatch)
  hipLaunchKernelGGL(prep_k, dim3(5632), dim3(256), 0, stream,
                     full_in, inputs, pos_emb, fibf, inbf, pebf,
                     W_kv, W_q, W_pos, W_proj, WkvT, WqT, WposT, WprojT, flags);

  // --- kv + q + r GEMMs, one dispatch (704 blocks)
  hipLaunchKernelGGL(gemm3_k, dim3(704), dim3(256), 0, stream,
                     fibf, WkvT, b_kv, Kt2, Vt2,
                     inbf, WqT, b_q, qq,
                     pebf, WposT, b_pos, Rt);

  // --- split-j fused attention + fence-free in-kernel combine
  hipLaunchKernelGGL(flash_k, dim3(16, 4, 16), dim3(256), 0, stream,
                     qq, Kt2, Vt2, Rt, u, v, po, pm, pl, av, flags);

  // --- output projection, split-K x2 with last-arriver merge
  hipLaunchKernelGGL(gemm_proj_k, dim3(256), dim3(256), 0, stream,
                     av, WprojT, b_proj, out, po, flags + 512);
}

// Round 13
// 224.155 us; speedup vs baseline: 1.0563x; 1.0563x over previous
//
#include <hip/hip_runtime.h>

// AttentionXL (TransformerXL relative attention), MI355X gfx950.
// Round 24: RESUBMIT of round 23 (bench infra failed twice; no counters).
// Round-6 five-dispatch structure with ONE isolated change: GEMM M-tile
// 128->64 (64x128 tiles). gemm3 was grid-limited (704 blocks = 2.75/CU,
// occupancy 22%): during each K-step's vmcnt-drain there were too few
// co-resident blocks to overlap (m114 wave-level TLP). Now gemm3 = 1408
// blocks (5.5/CU), proj = 256 (1/CU); per-block acc 2x4 (~70 VGPR), LDS
// 24KB. Same packed staging (contiguous 1KB DMA), same epilogue formulas.

typedef unsigned short u16;
typedef short short8 __attribute__((ext_vector_type(8)));
typedef float f32x4 __attribute__((ext_vector_type(4)));

#define BSZ 4
#define PREV 512

__device__ __forceinline__ float b2f(u16 u) {
  union { unsigned int i; float f; } x; x.i = ((unsigned int)u) << 16; return x.f;
}
__device__ __forceinline__ u16 f2b(float f) {
  union { float f; unsigned int i; } x; x.f = f;
  unsigned int u = x.i;
  return (u16)((u + 0x7fffu + ((u >> 16) & 1u)) >> 16);
}
__device__ __forceinline__ void storeC(u16* C, size_t idx, float v) { C[idx] = f2b(v); }
__device__ __forceinline__ void storeC(float* C, size_t idx, float v) { C[idx] = v; }

// async 16B/lane global->LDS DMA; lds dest = wave-uniform base + lane*16
__device__ __forceinline__ void load_lds16(const u16* g, void* l) {
  __builtin_amdgcn_global_load_lds(
      (const __attribute__((address_space(1))) unsigned int*)g,
      (__attribute__((address_space(3))) unsigned int*)l, 16, 0, 0);
}

// Packed operand layout: matrix [R][K] tiled into 16x32 chunks of 512 u16.
// chunk = (row/16)*(K/32) + k/32; within-chunk = frag order
// [quad=(k>>3)&3][ml=row&15][e=k&7].
__device__ __forceinline__ size_t pidx8(int row, int k, int K32) {
  return (((size_t)((row >> 4) * K32 + (k >> 5))) << 9) +
         (((k >> 3) & 3) << 7) + ((row & 15) << 3);
}

// ---------------------------------------------------------------------------
// prep: convert (blocks 0..3583) + weight transpose (3584..5631), packed out.
// ---------------------------------------------------------------------------
__global__ __launch_bounds__(256)
void prep_k(const float* __restrict__ s0, const float* __restrict__ s1,
            const float* __restrict__ s2, u16* __restrict__ d0,
            u16* __restrict__ d1, u16* __restrict__ d2,
            const float* __restrict__ W0, const float* __restrict__ W1,
            const float* __restrict__ W2, const float* __restrict__ W3,
            u16* __restrict__ T0, u16* __restrict__ T1,
            u16* __restrict__ T2, u16* __restrict__ T3) {
  __shared__ u16 ld[64 * 66];
  const int bxg = blockIdx.x, tid = threadIdx.x;
  if (bxg < 3584) {
    const float* s; u16* d; size_t base;
    if (bxg < 2048)      { s = s0; d = d0; base = (size_t)bxg * 2048; }
    else if (bxg < 3072) { s = s1; d = d1; base = (size_t)(bxg - 2048) * 2048; }
    else                 { s = s2; d = d2; base = (size_t)(bxg - 3072) * 2048; }
    size_t i = base + (size_t)tid * 8;
    const f32x4* p = reinterpret_cast<const f32x4*>(s + i);
    f32x4 a = p[0], b = p[1];
    short8 r;
#pragma unroll
    for (int e = 0; e < 4; e++) { r[e] = (short)f2b(a[e]); r[e + 4] = (short)f2b(b[e]); }
    int row = (int)(i >> 10), k = (int)(i & 1023);
    *reinterpret_cast<short8*>(d + pidx8(row, k, 32)) = r;
    return;
  }
  const int l = bxg - 3584;
  const int z = l >> 9;
  const int rem = l & 511;
  const int bx = rem & 31, by = rem >> 5;
  const float* W; u16* T; int N;
  if (z == 0)      { W = W0; T = T0; N = 2048; }
  else if (z == 1) { W = W1; T = T1; N = 1024; }
  else if (z == 2) { W = W2; T = T2; N = 1024; }
  else             { W = W3; T = T3; N = 1024; }
  const int n0 = bx * 64, k0 = by * 64;
  if (n0 >= N) return;

#pragma unroll
  for (int rep = 0; rep < 16; rep++) {
    int idx = tid + 256 * rep;
    int kk = idx >> 6, nn = idx & 63;
    ld[kk * 66 + nn] = f2b(W[(size_t)(k0 + kk) * N + n0 + nn]);
  }
  __syncthreads();
#pragma unroll
  for (int rep = 0; rep < 2; rep++) {
    int idx = tid + 256 * rep;           // 0..511
    int nn = idx >> 3, k8 = (idx & 7) * 8;
    short8 r;
#pragma unroll
    for (int e = 0; e < 8; e++) r[e] = (short)ld[(k8 + e) * 66 + nn];
    *reinterpret_cast<short8*>(T + pidx8(n0 + nn, k0 + k8, 32)) = r;
  }
}

// ---------------------------------------------------------------------------
// GEMM core, 64x128 tile, BK=64, packed A/BT. 4 waves: wave (wr=w>>1,
// wc=w&1) owns a 32x64 sub-tile (acc 2x4). Staging per wave per K-step:
// A 2 chunks + B 4 chunks (contiguous 1KB DMA each).
// MODE 0: row-major C. MODE 1 (kv): Kt2/Vt2 frag-tile order. MODE 2: Rt.
// ---------------------------------------------------------------------------
template <typename OT, int MODE>
__device__ __forceinline__ void gemm_core64(
    short* __restrict__ at, short* __restrict__ bt,
    const u16* __restrict__ A, const u16* __restrict__ BT,
    const float* __restrict__ bias, OT* __restrict__ C, u16* __restrict__ C2,
    int N, int K, int bx, int by)
{
  const int tid = threadIdx.x;
  const int lane = tid & 63, w = tid >> 6;
  const int wr = w >> 1, wc = w & 1;
  const int quad = lane >> 4, ml = lane & 15;
  const int row0 = by * 64, col0 = bx * 128;
  const int K32 = K >> 5;

  f32x4 acc[2][4];
  const f32x4 fzero = {0.f, 0.f, 0.f, 0.f};
#pragma unroll
  for (int i = 0; i < 2; i++)
#pragma unroll
    for (int j = 0; j < 4; j++) acc[i][j] = fzero;

  for (int k0 = 0; k0 < K; k0 += 64) {
    __syncthreads();  // previous tile fully consumed
#pragma unroll
    for (int i = 0; i < 2; i++) {        // A: 8 chunks total, 2 per wave
      int c = 2 * w + i;
      int mcg = c >> 1, kc = c & 1;
      size_t ca = ((size_t)(((row0 >> 4) + mcg) * K32 + (k0 >> 5) + kc)) << 9;
      load_lds16(A + ca + lane * 8, (void*)(at + c * 512));
    }
#pragma unroll
    for (int i = 0; i < 4; i++) {        // B: 16 chunks total, 4 per wave
      int c = 4 * w + i;
      int mcg = c >> 1, kc = c & 1;
      size_t cb = ((size_t)(((col0 >> 4) + mcg) * K32 + (k0 >> 5) + kc)) << 9;
      load_lds16(BT + cb + lane * 8, (void*)(bt + c * 512));
    }
    __syncthreads();  // drains vmcnt; staging visible

    short8 af[2][2], bf[4][2];
#pragma unroll
    for (int mc = 0; mc < 2; mc++)
#pragma unroll
      for (int kc = 0; kc < 2; kc++)
        af[mc][kc] = *reinterpret_cast<const short8*>(at + ((((wr * 2 + mc) * 2 + kc) * 64) + lane) * 8);
#pragma unroll
    for (int nc = 0; nc < 4; nc++)
#pragma unroll
      for (int kc = 0; kc < 2; kc++)
        bf[nc][kc] = *reinterpret_cast<const short8*>(bt + ((((wc * 4 + nc) * 2 + kc) * 64) + lane) * 8);

#pragma unroll
    for (int mc = 0; mc < 2; mc++)
#pragma unroll
      for (int nc = 0; nc < 4; nc++)
#pragma unroll
        for (int kc = 0; kc < 2; kc++)
          acc[mc][nc] = __builtin_amdgcn_mfma_f32_16x16x32_bf16(af[mc][kc], bf[nc][kc], acc[mc][nc], 0, 0, 0);
  }

#pragma unroll
  for (int nc = 0; nc < 4; nc++) {
    int col = col0 + wc * 64 + nc * 16 + ml;
    float bv = bias[col];
#pragma unroll
    for (int mc = 0; mc < 2; mc++) {
#pragma unroll
      for (int reg = 0; reg < 4; reg++) {
        int row = row0 + wr * 32 + mc * 16 + quad * 4 + reg;
        float val = acc[mc][nc][reg] + bv;
        if constexpr (MODE == 0) {
          storeC(C, (size_t)row * N + col, val);
        } else if constexpr (MODE == 1) {
          int j = row >> 2, bb = row & 3;
          int tile = j >> 6, jl = j & 63;
          if (col < 1024) {  // K half: frag (n=j, k=d)
            int h = col >> 6, d = col & 63;
            int ncj = jl >> 4, nlj = jl & 15, kcd = d >> 5, qdd = (d >> 3) & 3, jjd = d & 7;
            C[((size_t)(bb * 16 + h) * 16 + tile) * 4096 +
              ((ncj * 2 + kcd) * 64 + qdd * 16 + nlj) * 8 + jjd] = f2b(val);
          } else {           // V half: frag (n=d, k=j)
            int c2 = col - 1024;
            int h = c2 >> 6, d = c2 & 63;
            int ncd = d >> 4, nld = d & 15, kcj = jl >> 5, qdj = (jl >> 3) & 3, jjj = jl & 7;
            C2[((size_t)(bb * 16 + h) * 16 + tile) * 4096 +
               ((kcj * 4 + ncd) * 64 + qdj * 16 + nld) * 8 + jjj] = f2b(val);
          }
        } else {             // MODE 2: Rt[h][rel][d]
          int h = col >> 6, d = col & 63;
          C[((size_t)h * 1024 + row) * 64 + d] = f2b(val);
        }
      }
    }
  }
}

// ---------------------------------------------------------------------------
// gemm3: kv (1024 blocks) + q (256) + r (128) in one 1408-block dispatch.
// ---------------------------------------------------------------------------
__global__ __launch_bounds__(256, 2)
void gemm3_k(const u16* __restrict__ fibf, const u16* __restrict__ WkvT,
             const float* __restrict__ b_kv, u16* __restrict__ Kt2, u16* __restrict__ Vt2,
             const u16* __restrict__ inbf, const u16* __restrict__ WqT,
             const float* __restrict__ b_q, u16* __restrict__ qq,
             const u16* __restrict__ pebf, const u16* __restrict__ WposT,
             const float* __restrict__ b_pos, u16* __restrict__ Rt)
{
  __shared__ __align__(16) short at[4096];
  __shared__ __align__(16) short bt[8192];
  const int id = blockIdx.x;
  if (id < 1024) {        // kv: M=4096 (64 row-tiles) x N=2048 (16 col-tiles)
    gemm_core64<u16, 1>(at, bt, fibf, WkvT, b_kv, Kt2, Vt2, 2048, 1024,
                        id & 15, id >> 4);
  } else if (id < 1280) { // q: M=2048 (32) x N=1024 (8)
    const int l = id - 1024;
    gemm_core64<u16, 0>(at, bt, inbf, WqT, b_q, qq, (u16*)nullptr, 1024, 1024,
                        l & 7, l >> 3);
  } else {                // r: M=1024 (16) x N=1024 (8)
    const int l = id - 1280;
    gemm_core64<u16, 2>(at, bt, pebf, WposT, b_pos, Rt, (u16*)nullptr, 1024, 1024,
                        l & 7, l >> 3);
  }
}

// ---------------------------------------------------------------------------
// proj: M=2048 (32 row-tiles) x N=1024 (8 col-tiles) = 256 blocks.
// ---------------------------------------------------------------------------
__global__ __launch_bounds__(256, 2)
void gemm_proj_k(const u16* __restrict__ A, const u16* __restrict__ BT,
                 const float* __restrict__ bias, float* __restrict__ C)
{
  __shared__ __align__(16) short at[4096];
  __shared__ __align__(16) short bt[8192];
  const int id = blockIdx.x;
  gemm_core64<float, 0>(at, bt, A, BT, bias, C, (u16*)nullptr, 1024, 1024,
                        id & 7, id >> 3);
}

// ---------------------------------------------------------------------------
// Split-j fused flash-XL (round-6 proven): 16 blocks/bh, longest-first,
// 4 blocks/CU all-resident; ones-MFMA row-sum; plain partial writes.
// ---------------------------------------------------------------------------
__global__ __launch_bounds__(256, 4)
void flash_k(const u16* __restrict__ q, const u16* __restrict__ Kt2,
             const u16* __restrict__ Vt2, const u16* __restrict__ Rt,
             const float* __restrict__ u, const float* __restrict__ v,
             float* __restrict__ po, float* __restrict__ pm,
             float* __restrict__ pl)
{
  __shared__ __align__(16) short kb[4096];
  __shared__ __align__(16) short vb[4096];
  __shared__ __align__(16) short pt[4][1024];

  const int tid = threadIdx.x, lane = tid & 63, w = tid >> 6;
  short* ptw = pt[w];
  const int quad = lane >> 4, ml = lane & 15;
  const int x = blockIdx.x;
  const int it = 7 - (x >> 1), s = x & 1;     // longest i-tiles first
  const int nt = it + 9;
  const int nt0 = (nt + 1) >> 1;
  const int ts = s ? nt0 : 0, te = s ? nt : nt0;

  const int b = blockIdx.y, h = blockIdx.z;
  const int bh = b * 16 + h;
  const int i0 = it * 64, ig0 = i0 + w * 16;

  const u16* Kbase = Kt2 + ((size_t)(b * 16 + h) * 16) * 4096;
  const u16* Vbase = Vt2 + ((size_t)(b * 16 + h) * 16) * 4096;
  const u16* Rp = Rt + (size_t)h * 65536;

  // Q fragments, pre-scaled by 1/8: rows ig0+ml, k = kc*32+quad*8+e
  short8 qu[2], qvf[2];
  {
    int ig = ig0 + ml;
#pragma unroll
    for (int kc = 0; kc < 2; kc++) {
      int dbase = kc * 32 + quad * 8;
      short8 qq = *reinterpret_cast<const short8*>(q + ((size_t)ig * BSZ + b) * 1024 + h * 64 + dbase);
      const f32x4* up = reinterpret_cast<const f32x4*>(u + h * 64 + dbase);
      const f32x4* vp = reinterpret_cast<const f32x4*>(v + h * 64 + dbase);
      f32x4 u0 = up[0], u1 = up[1], v0 = vp[0], v1 = vp[1];
#pragma unroll
      for (int e = 0; e < 8; e++) {
        float qf = b2f((u16)qq[e]);
        float uu = (e < 4) ? u0[e] : u1[e - 4];
        float vv = (e < 4) ? v0[e] : v1[e - 4];
        qu[kc][e]  = (short)f2b((qf + uu) * 0.125f);
        qvf[kc][e] = (short)f2b((qf + vv) * 0.125f);
      }
    }
  }

  short8 kones;
#pragma unroll
  for (int e = 0; e < 8; e++) kones[e] = (short)0x3F80;

  const f32x4 fzero = {0.f, 0.f, 0.f, 0.f};
  f32x4 o_acc[4];
#pragma unroll
  for (int i = 0; i < 4; i++) o_acc[i] = fzero;
  float m_run[4], l_run[4];
#pragma unroll
  for (int i = 0; i < 4; i++) { m_run[i] = -1e30f; l_run[i] = 0.f; }

  // ---- prologue: prefetch tile ts's identity chunks into registers
  short8 pk0, pk1, pv0, pv1;
  {
    const u16* kg = Kbase + (size_t)ts * 4096;
    const u16* vg = Vbase + (size_t)ts * 4096;
    pk0 = *reinterpret_cast<const short8*>(kg + tid * 8);
    pk1 = *reinterpret_cast<const short8*>(kg + 2048 + tid * 8);
    pv0 = *reinterpret_cast<const short8*>(vg + tid * 8);
    pv1 = *reinterpret_cast<const short8*>(vg + 2048 + tid * 8);
  }

  for (int t = ts; t < te; t++) {
    const int j0 = t * 64;
    __syncthreads();  // previous tile fully consumed
    *reinterpret_cast<short8*>(kb + tid * 8) = pk0;
    *reinterpret_cast<short8*>(kb + 2048 + tid * 8) = pk1;
    *reinterpret_cast<short8*>(vb + tid * 8) = pv0;
    *reinterpret_cast<short8*>(vb + 2048 + tid * 8) = pv1;
    __syncthreads();  // staging visible

    if (t + 1 < te) {
      const u16* kg = Kbase + (size_t)(t + 1) * 4096;
      const u16* vg = Vbase + (size_t)(t + 1) * 4096;
      pk0 = *reinterpret_cast<const short8*>(kg + tid * 8);
      pk1 = *reinterpret_cast<const short8*>(kg + 2048 + tid * 8);
      pv0 = *reinterpret_cast<const short8*>(vg + tid * 8);
      pv1 = *reinterpret_cast<const short8*>(vg + 2048 + tid * 8);
    }

    // ---- content scores: K B-frags from LDS
    f32x4 sc[4];
#pragma unroll
    for (int nc = 0; nc < 4; nc++) {
      sc[nc] = fzero;
#pragma unroll
      for (int kc = 0; kc < 2; kc++) {
        short8 kf = *reinterpret_cast<const short8*>(kb + ((nc * 2 + kc) * 64 + lane) * 8);
        sc[nc] = __builtin_amdgcn_mfma_f32_16x16x32_bf16(qu[kc], kf, sc[nc], 0, 0, 0);
      }
    }
    // ---- position strip: R B-frags direct from global
    const int relstart = j0 - ig0 + 496;  // >= 0
    f32x4 p2[5];
#pragma unroll
    for (int c = 0; c < 5; c++) {
      p2[c] = fzero;
      int rel = relstart + c * 16 + ml;
      if (rel > 1023) rel = 1023;  // clamped rows are masked below
      const u16* rp = Rp + (size_t)rel * 64 + quad * 8;
#pragma unroll
      for (int kc = 0; kc < 2; kc++) {
        short8 rf = *reinterpret_cast<const short8*>(rp + kc * 32);
        p2[c] = __builtin_amdgcn_mfma_f32_16x16x32_bf16(qvf[kc], rf, p2[c], 0, 0, 0);
      }
    }

    // ---- rel-shift gather + mask + online softmax
    const bool anymask = (j0 + 63) > (ig0 + PREV);
    float pv_[4][4];
    float tmax[4] = {-1e30f, -1e30f, -1e30f, -1e30f};
#pragma unroll
    for (int reg = 0; reg < 4; reg++) {
      int rowl = quad * 4 + reg;
      int src = quad * 16 + ((ml - rowl - 1) & 15);
      bool hi = ml > rowl;
      float sh[5];
#pragma unroll
      for (int c = 0; c < 5; c++) sh[c] = __shfl(p2[c][reg], src, 64);
#pragma unroll
      for (int nc = 0; nc < 4; nc++) {
        float sv = sc[nc][reg] + (hi ? sh[nc + 1] : sh[nc]);
        if (anymask) {
          int jg = j0 + nc * 16 + ml;
          if (jg > ig0 + rowl + PREV) sv = -1e30f;
        }
        pv_[nc][reg] = sv;
        tmax[reg] = fmaxf(tmax[reg], sv);
      }
    }
    // ---- row-max butterfly + exp; l-sum deferred to the ones-MFMA below
#pragma unroll
    for (int reg = 0; reg < 4; reg++) {
      float tm = tmax[reg];
#pragma unroll
      for (int off = 1; off < 16; off <<= 1) tm = fmaxf(tm, __shfl_xor(tm, off, 64));
      float mnew = fmaxf(m_run[reg], tm);
      float alpha = __expf(m_run[reg] - mnew);
#pragma unroll
      for (int nc = 0; nc < 4; nc++)
        pv_[nc][reg] = __expf(pv_[nc][reg] - mnew);
      l_run[reg] *= alpha;
      m_run[reg] = mnew;
#pragma unroll
      for (int nc = 0; nc < 4; nc++) o_acc[nc][reg] *= alpha;
    }

    // ---- P (C layout) -> bf16 A-frag via per-wave LDS
#pragma unroll
    for (int nc = 0; nc < 4; nc++) {
      int jl = nc * 16 + ml;
      int kc = nc >> 1, qdj = (jl >> 3) & 3, jj = ml & 7;
#pragma unroll
      for (int reg = 0; reg < 4; reg++) {
        int rowl = quad * 4 + reg;
        ptw[(kc * 64 + qdj * 16 + rowl) * 8 + jj] = (short)f2b(pv_[nc][reg]);
      }
    }
    short8 pf[2];
    pf[0] = *reinterpret_cast<const short8*>(ptw + (0 * 64 + lane) * 8);
    pf[1] = *reinterpret_cast<const short8*>(ptw + (1 * 64 + lane) * 8);

    // ---- row-sum of P via ones-MFMA (concurrent with PV on the MFMA pipe)
    f32x4 lsum = fzero;
    lsum = __builtin_amdgcn_mfma_f32_16x16x32_bf16(pf[0], kones, lsum, 0, 0, 0);
    lsum = __builtin_amdgcn_mfma_f32_16x16x32_bf16(pf[1], kones, lsum, 0, 0, 0);

    // ---- PV: V B-frags from LDS
#pragma unroll
    for (int ncd = 0; ncd < 4; ncd++)
#pragma unroll
      for (int kc = 0; kc < 2; kc++) {
        short8 vf = *reinterpret_cast<const short8*>(vb + ((kc * 4 + ncd) * 64 + lane) * 8);
        o_acc[ncd] = __builtin_amdgcn_mfma_f32_16x16x32_bf16(pf[kc], vf, o_acc[ncd], 0, 0, 0);
      }
#pragma unroll
    for (int reg = 0; reg < 4; reg++) l_run[reg] += lsum[reg];
  }

  // ---- write unnormalized partials: ridx = (s*512+ig)*64 + bh
#pragma unroll
  for (int reg = 0; reg < 4; reg++) {
    int ig = ig0 + quad * 4 + reg;
    size_t ridx = (size_t)(s * 512 + ig) * 64 + bh;
    if (ml == 0) { pm[ridx] = m_run[reg]; pl[ridx] = l_run[reg]; }
#pragma unroll
    for (int ncd = 0; ncd < 4; ncd++)
      po[ridx * 64 + ncd * 16 + ml] = o_acc[ncd][reg];
  }
}

// ---------------------------------------------------------------------------
// Merge the two j-segments; write av in PACKED layout for the proj GEMM.
// ---------------------------------------------------------------------------
__global__ __launch_bounds__(256)
void combine_k(const float* __restrict__ po, const float* __restrict__ pm,
               const float* __restrict__ pl, u16* __restrict__ av) {
  int t = blockIdx.x * 256 + threadIdx.x;    // 262,144 total
  int r0 = t >> 3, d8 = (t & 7) * 8;         // r0 = ig*64 + b*16 + h
  int ig = r0 >> 6, b = (r0 >> 4) & 3, h = r0 & 15;
  float m1 = pm[r0], m2 = pm[32768 + r0];
  float l1 = pl[r0], l2 = pl[32768 + r0];
  const f32x4* p1 = reinterpret_cast<const f32x4*>(po + (size_t)r0 * 64 + d8);
  const f32x4* p2 = reinterpret_cast<const f32x4*>(po + ((size_t)32768 + r0) * 64 + d8);
  f32x4 o1a = p1[0], o1b = p1[1], o2a = p2[0], o2b = p2[1];
  float m = fmaxf(m1, m2);
  float a1 = __expf(m1 - m), a2 = __expf(m2 - m);
  float l = l1 * a1 + l2 * a2;
  short8 r;
#pragma unroll
  for (int e = 0; e < 4; e++) {
    r[e]     = (short)f2b((o1a[e] * a1 + o2a[e] * a2) / l);
    r[e + 4] = (short)f2b((o1b[e] * a1 + o2b[e] * a2) / l);
  }
  int row = ig * 4 + b, k = h * 64 + d8;
  *reinterpret_cast<short8*>(av + pidx8(row, k, 32)) = r;
}

// ---------------------------------------------------------------------------
extern "C" void kernel_launch(void* const* d_in, const int* in_sizes, int n_in,
                              void* d_out, int out_size, void* d_ws, size_t ws_size,
                              hipStream_t stream) {
  (void)in_sizes; (void)n_in; (void)out_size; (void)ws_size;

  const float* inputs  = (const float*)d_in[0];   // (512,4,1024)
  const float* pos_emb = (const float*)d_in[1];   // (1024,1,1024)
  const float* full_in = (const float*)d_in[2];   // (1024,4,1024)
  const float* u       = (const float*)d_in[3];   // (16,64)
  const float* v       = (const float*)d_in[4];   // (16,64)
  const float* W_kv    = (const float*)d_in[5];   // (1024,2048)
  const float* b_kv    = (const float*)d_in[6];   // (2048,)
  const float* W_q     = (const float*)d_in[7];   // (1024,1024)
  const float* b_q     = (const float*)d_in[8];
  const float* W_pos   = (const float*)d_in[9];   // (1024,1024)
  const float* b_pos   = (const float*)d_in[10];
  const float* W_proj  = (const float*)d_in[11];  // (1024,1024)
  const float* b_proj  = (const float*)d_in[12];
  float* out = (float*)d_out;
  char* ws = (char*)d_ws;

  u16* Kt2   = (u16*)(ws);                  //  8 MB: frag-tile order
  u16* Vt2   = (u16*)(ws + ( 8u << 20));    //  8 MB
  u16* qq    = (u16*)(ws + (16u << 20));    //  4 MB row-major
  u16* Rt    = (u16*)(ws + (20u << 20));    //  2 MB [16 h][1024 rel][64 d]
  u16* av    = (u16*)(ws + (22u << 20));    //  4 MB packed
  u16* WkvT  = (u16*)(ws + (26u << 20));    //  4 MB packed
  u16* WqT   = (u16*)(ws + (30u << 20));    //  2 MB packed
  u16* WposT = (u16*)(ws + (32u << 20));    //  2 MB packed
  u16* WprojT= (u16*)(ws + (34u << 20));    //  2 MB packed
  u16* fibf  = (u16*)(ws + (36u << 20));    //  8 MB packed (dead after gemm3)
  u16* inbf  = (u16*)(ws + (44u << 20));    //  4 MB packed (dead after gemm3)
  u16* pebf  = (u16*)(ws + (48u << 20));    //  2 MB packed (dead after gemm3)
  float* po  = (float*)(ws + (36u << 20));  // 16 MB partial O (2 slots; overlays the above)
  float* pm  = (float*)(ws + (52u << 20));  // 256 KB partial m
  float* pl  = (float*)(ws + (52u << 20) + (256u << 10));  // 256 KB partial l

  // --- precompute (converts + weight transposes, one dispatch)
  hipLaunchKernelGGL(prep_k, dim3(5632), dim3(256), 0, stream,
                     full_in, inputs, pos_emb, fibf, inbf, pebf,
                     W_kv, W_q, W_pos, W_proj, WkvT, WqT, WposT, WprojT);

  // --- kv + q + r GEMMs, one dispatch (1408 blocks, 64x128 tiles)
  hipLaunchKernelGGL(gemm3_k, dim3(1408), dim3(256), 0, stream,
                     fibf, WkvT, b_kv, Kt2, Vt2,
                     inbf, WqT, b_q, qq,
                     pebf, WposT, b_pos, Rt);

  // --- split-j fused attention + combine
  hipLaunchKernelGGL(flash_k, dim3(16, 4, 16), dim3(256), 0, stream,
                     qq, Kt2, Vt2, Rt, u, v, po, pm, pl);
  hipLaunchKernelGGL(combine_k, dim3(1024), dim3(256), 0, stream, po, pm, pl, av);

  // --- output projection (256 blocks, 64x128 tiles)
  hipLaunchKernelGGL(gemm_proj_k, dim3(256), dim3(256), 0, stream,
                     av, WprojT, b_proj, out);
}